// Round 14
// baseline (130.864 us; speedup 1.0000x reference)
//
#include <hip/hip_runtime.h>
#include <hip/hip_bf16.h>
#include <cstddef>

#define HW 2304
#define CD 256

typedef __bf16 bf16;
typedef bf16 bf16x8 __attribute__((ext_vector_type(8)));
typedef float f32x4 __attribute__((ext_vector_type(4)));

__device__ __forceinline__ unsigned short f2bf(float f) {
    unsigned u = __float_as_uint(f);
    u += 0x7fffu + ((u >> 16) & 1u);
    return (unsigned short)(u >> 16);
}

// ---- pass 1 (fused): convert mems + transpose k + coarse dots ----
// New layouts for the 256x256 BK=64 GEMM:
//   memsB[z][kt64 (0..3)][n][64], kT[b][kt64][m][64], with the 16B chunk
//   XOR-swizzle baked in: phys_chunk = (k64/8) ^ (row & 7).
// blocks [0,9216): convert; [9216,11520): transpose; [11520,11556): coarse
__global__ void prep(const float* __restrict__ g0, const float* __restrict__ g1,
                     const float* __restrict__ l0, const float* __restrict__ l1,
                     const float* __restrict__ k,
                     const float* __restrict__ c0, const float* __restrict__ c1,
                     const float* __restrict__ c2, const float* __restrict__ c3,
                     const float* __restrict__ c4, const float* __restrict__ c5,
                     unsigned short* __restrict__ outB,
                     unsigned short* __restrict__ kT,
                     float* __restrict__ out) {
    __shared__ float tile[32][33];
    const int bid = blockIdx.x;
    const int tid = threadIdx.x;
    if (bid < 9216) {
        const int bx = bid % 576, z = bid / 576;
        const int b = z >> 2, t = z & 3;
        const float* src = t == 0 ? g0 : t == 1 ? g1 : t == 2 ? l0 : l1;
        const int i4 = bx * 256 + tid;        // [0, 147456)
        const int n = i4 >> 6;
        const int q = i4 & 63;                // float4 index within row
        const int kt4 = q >> 4;               // K-tile of 64
        const int kk64 = (q & 15) * 4;        // elem offset within 64
        float4 v = *(const float4*)(src + (size_t)b * (HW * CD) + (size_t)n * CD + q * 4);
        ushort4 o;
        o.x = f2bf(v.x); o.y = f2bf(v.y); o.z = f2bf(v.z); o.w = f2bf(v.w);
        const int cl = kk64 >> 3;
        const int phys = (((cl ^ (n & 7)) << 3) | (kk64 & 7));
        *(ushort4*)(outB + (size_t)z * (HW * CD) + (size_t)kt4 * (HW * 64)
                    + (size_t)n * 64 + phys) = o;
    } else if (bid < 11520) {
        const int t3 = bid - 9216;              // orig grid (72,8,4)
        const int m0 = (t3 % 72) * 32;
        const int c0_ = ((t3 / 72) & 7) * 32;
        const int bz = t3 / 576;
        const int tx = tid & 31, ty = tid >> 5;
        const float* kb = k + (size_t)bz * CD * HW;
        #pragma unroll
        for (int s = 0; s < 32; s += 8)
            tile[ty + s][tx] = kb[(size_t)(c0_ + ty + s) * HW + m0 + tx];
        __syncthreads();
        unsigned short* kTb = kT + (size_t)bz * (HW * CD);
        #pragma unroll
        for (int s = 0; s < 32; s += 8) {
            const int m = m0 + ty + s;
            const int c = c0_ + tx;
            const int kt4 = c >> 6;
            const int kk64 = c & 63;
            const int cl = kk64 >> 3;
            const int phys = (((cl ^ (m & 7)) << 3) | (kk64 & 7));
            kTb[(size_t)kt4 * (HW * 64) + (size_t)m * 64 + phys] = f2bf(tile[tx][ty + s]);
        }
    } else {
        const int g = (bid - 11520) * 256 + tid;   // 36*256 = 9216 = 4*HW
        const int b = g / HW, m = g - b * HW;
        float a0 = 0, a1 = 0, a2 = 0, a3 = 0, a4 = 0, a5 = 0;
        const float* kb = k + (size_t)b * CD * HW;
        for (int c = 0; c < CD; ++c) {
            const float kv = kb[(size_t)c * HW + m];
            a0 = fmaf(c0[b * CD + c], kv, a0);
            a1 = fmaf(c1[b * CD + c], kv, a1);
            a2 = fmaf(c2[b * CD + c], kv, a2);
            a3 = fmaf(c3[b * CD + c], kv, a3);
            a4 = fmaf(c4[b * CD + c], kv, a4);
            a5 = fmaf(c5[b * CD + c], kv, a5);
        }
        out[((size_t)b * 10 + 4) * HW + m] = a0;
        out[((size_t)b * 10 + 5) * HW + m] = a1;
        out[((size_t)b * 10 + 6) * HW + m] = a2;
        out[((size_t)b * 10 + 7) * HW + m] = a3;
        out[((size_t)b * 10 + 8) * HW + m] = a4;
        out[((size_t)b * 10 + 9) * HW + m] = a5;
    }
}

// ---- pass 2: 256x256 8-phase GEMM (m201 template port) ----
// 512 threads = 8 waves (2M x 4N); BK=64; LDS 128KB (2buf x 2half x 128x64 x A,B).
// Per phase: ds_reads (compiler-scheduled lgkm) + 1 half-tile global_load_lds
// + setprio'd 16-MFMA cluster + raw s_barrier (memory-pinned, NO vmcnt drain).
// Counted vmcnt(4) once per K-tile, before the barrier preceding the reads.
// grid 1296: x=h&7 -> XCD slot; b=x>>1; t=(x&1)*2+(j&1) (t-pairs share sds via L2).
__global__ __launch_bounds__(512, 2)
void fine_gemm(const unsigned short* __restrict__ memsB,  // [z][kt64][2304][64] swz
               const unsigned short* __restrict__ kT,     // [b][kt64][2304][64] swz
               const float* __restrict__ sds,
               float* __restrict__ part) {
    __shared__ unsigned short Asm[2][2][128][64];   // 64KB [buf][half][row][col]
    __shared__ unsigned short Bsm[2][2][128][64];   // 64KB

    const int h = blockIdx.x;
    const int x = h & 7, j = h >> 3;     // j in [0,162)
    const int b = x >> 1;
    const int t = (x & 1) * 2 + (j & 1);
    const int tile = j >> 1;             // [0,81)
    const int mi = tile % 9, ni = tile / 9;
    const int z = b * 4 + t;
    const int n0 = ni * 256, m0 = mi * 256;

    const int tid = threadIdx.x;
    const int lane = tid & 63;
    const int w = tid >> 6;              // 0..7
    const int wm = w >> 2, wn = w & 3;

    const unsigned short* Ag = memsB + (size_t)z * (HW * CD);
    const unsigned short* Bg = kT + (size_t)b * (HW * CD);

    const int rA = lane & 15;
    const int g4 = lane >> 4;
    const int cp0 = g4 ^ (rA & 7);       // phys chunk, ks=0
    const int cp1 = cp0 ^ 4;             // ks=1
    const int rB0 = (wn & 1) * 64 + rA;  // B row base within half
    const int bh = wn >> 1;              // B half for this wave
    const size_t so = (size_t)w * 2048 + (size_t)lane * 16;   // stage byte offset

    f32x4 acc[8][4] = {};
    bf16x8 bF0[4], bF1[4];

#define GLDS(gp, lp)                                                                       \
    __builtin_amdgcn_global_load_lds(                                                      \
        (const __attribute__((address_space(1))) unsigned int*)(gp),                       \
        (__attribute__((address_space(3))) unsigned int*)(lp), 16, 0, 0)

#define STG_A(buf, hh, kt_)                                                                \
    do {                                                                                   \
        const char* g_ = (const char*)(Ag + (size_t)(kt_) * (HW * 64)                      \
                         + (size_t)(n0 + (hh) * 128) * 64) + so;                           \
        char* l_ = (char*)&Asm[buf][hh][w * 16][0];                                        \
        GLDS(g_, l_); GLDS(g_ + 1024, l_ + 1024);                                          \
    } while (0)

#define STG_B(buf, hh, kt_)                                                                \
    do {                                                                                   \
        const char* g_ = (const char*)(Bg + (size_t)(kt_) * (HW * 64)                      \
                         + (size_t)(m0 + (hh) * 128) * 64) + so;                           \
        char* l_ = (char*)&Bsm[buf][hh][w * 16][0];                                        \
        GLDS(g_, l_); GLDS(g_ + 1024, l_ + 1024);                                          \
    } while (0)

#define A_FRAG(buf, mf, cp) \
    (*(const bf16x8*)((const char*)&Asm[buf][wm][0][0] + ((mf) * 16 + rA) * 128 + (cp) * 16))
#define B_FRAG(buf, nf, cp) \
    (*(const bf16x8*)((const char*)&Bsm[buf][bh][0][0] + (rB0 + (nf) * 16) * 128 + (cp) * 16))

#define BARRIER() asm volatile("s_barrier" ::: "memory")
#define VMCNT(n)  asm volatile("s_waitcnt vmcnt(" #n ")" ::: "memory")

#define PHASE(kt_, q, STAGE_CODE, ENDWAIT)                                                 \
    do {                                                                                   \
        const int buf_ = (kt_) & 1;                                                        \
        if ((q) == 0) {                                                                    \
            _Pragma("unroll")                                                              \
            for (int nf = 0; nf < 4; ++nf) {                                               \
                bF0[nf] = B_FRAG(buf_, nf, cp0);                                           \
                bF1[nf] = B_FRAG(buf_, nf, cp1);                                           \
            }                                                                              \
        }                                                                                  \
        bf16x8 a0k0 = A_FRAG(buf_, 2 * (q), cp0);                                          \
        bf16x8 a0k1 = A_FRAG(buf_, 2 * (q), cp1);                                          \
        bf16x8 a1k0 = A_FRAG(buf_, 2 * (q) + 1, cp0);                                      \
        bf16x8 a1k1 = A_FRAG(buf_, 2 * (q) + 1, cp1);                                      \
        STAGE_CODE;                                                                        \
        __builtin_amdgcn_s_setprio(1);                                                     \
        _Pragma("unroll")                                                                  \
        for (int nf = 0; nf < 4; ++nf) {                                                   \
            acc[2 * (q)][nf]     = __builtin_amdgcn_mfma_f32_16x16x32_bf16(a0k0, bF0[nf], acc[2 * (q)][nf], 0, 0, 0); \
            acc[2 * (q)][nf]     = __builtin_amdgcn_mfma_f32_16x16x32_bf16(a0k1, bF1[nf], acc[2 * (q)][nf], 0, 0, 0); \
            acc[2 * (q) + 1][nf] = __builtin_amdgcn_mfma_f32_16x16x32_bf16(a1k0, bF0[nf], acc[2 * (q) + 1][nf], 0, 0, 0); \
            acc[2 * (q) + 1][nf] = __builtin_amdgcn_mfma_f32_16x16x32_bf16(a1k1, bF1[nf], acc[2 * (q) + 1][nf], 0, 0, 0); \
        }                                                                                  \
        __builtin_amdgcn_s_setprio(0);                                                     \
        ENDWAIT;                                                                           \
        BARRIER();                                                                         \
    } while (0)

    // prologue: A(0), B(0) -> buf0; B(1) -> buf1   (12 loads/wave in flight)
    STG_A(0, 0, 0); STG_A(0, 1, 0);
    STG_B(0, 0, 0); STG_B(0, 1, 0);
    STG_B(1, 0, 1); STG_B(1, 1, 1);
    VMCNT(4);        // A(0),B(0) landed; B(1)'s 4 stay in flight
    BARRIER();

    // iter 0: compute kt 0,1; stage A(1)->Asm[1], B(2)->Bsm[0], A(2)->Asm[0], B(3)->Bsm[1]
    PHASE(0, 0, STG_A(1, 0, 1), (void)0);
    PHASE(0, 1, STG_A(1, 1, 1), (void)0);
    PHASE(0, 2, STG_B(0, 0, 2), (void)0);
    PHASE(0, 3, STG_B(0, 1, 2), VMCNT(4));   // A(1),B(1) landed; B(2) in flight
    PHASE(1, 0, STG_A(0, 0, 2), (void)0);
    PHASE(1, 1, STG_A(0, 1, 2), (void)0);
    PHASE(1, 2, STG_B(1, 0, 3), (void)0);
    PHASE(1, 3, STG_B(1, 1, 3), VMCNT(4));   // A(2),B(2) landed; B(3) in flight
    // iter 1: compute kt 2,3; stage A(3)->Asm[1]
    PHASE(2, 0, STG_A(1, 0, 3), (void)0);
    PHASE(2, 1, STG_A(1, 1, 3), (void)0);
    PHASE(2, 2, (void)0, (void)0);
    PHASE(2, 3, (void)0, VMCNT(0));          // A(3) is newest -> final drain
    PHASE(3, 0, (void)0, (void)0);
    PHASE(3, 1, (void)0, (void)0);
    PHASE(3, 2, (void)0, (void)0);
    PHASE(3, 3, (void)0, (void)0);

#undef PHASE
#undef STG_A
#undef STG_B
#undef GLDS

    // epilogue: sds scale for local memories (t >= 2)
    if (t >= 2) {
        const float* sb = sds + (size_t)b * HW * HW;
        #pragma unroll
        for (int mf = 0; mf < 8; ++mf) {
            #pragma unroll
            for (int nf = 0; nf < 4; ++nf) {
                #pragma unroll
                for (int r = 0; r < 4; ++r) {
                    const int n = n0 + wm * 128 + mf * 16 + g4 * 4 + r;
                    const int m = m0 + wn * 64 + nf * 16 + rA;
                    acc[mf][nf][r] *= sb[(size_t)n * HW + m];
                }
            }
        }
    }

    // column max over this wave's 128-row half; race-free per-(ni,wm) partials
    #pragma unroll
    for (int nf = 0; nf < 4; ++nf) {
        float v = acc[0][nf][0];
        #pragma unroll
        for (int mf = 0; mf < 8; ++mf)
            #pragma unroll
            for (int r = 0; r < 4; ++r)
                v = fmaxf(v, acc[mf][nf][r]);
        v = fmaxf(v, __shfl_xor(v, 16));
        v = fmaxf(v, __shfl_xor(v, 32));
        if (lane < 16) {
            const int m = m0 + wn * 64 + nf * 16 + lane;
            part[((size_t)z * 18 + ni * 2 + wm) * HW + m] = v;
        }
    }
}

// ---- pass 3: reduce partials over (ni, wm) ----
__global__ void finalize(const float* __restrict__ part, float* __restrict__ out) {
    const int i = blockIdx.x * 256 + threadIdx.x;   // 144*256 = 36864 = 16*HW
    const int z = i / HW, m = i - z * HW;
    const int b = z >> 2, t = z & 3;
    float v = part[(size_t)z * 18 * HW + m];
    #pragma unroll
    for (int q = 1; q < 18; ++q)
        v = fmaxf(v, part[((size_t)z * 18 + q) * HW + m]);
    out[((size_t)b * 10 + t) * HW + m] = v;
}

extern "C" void kernel_launch(void* const* d_in, const int* in_sizes, int n_in,
                              void* d_out, int out_size, void* d_ws, size_t ws_size,
                              hipStream_t stream) {
    const float* norm_key = (const float*)d_in[0];
    const float* gbg = (const float*)d_in[1];
    const float* gfg = (const float*)d_in[2];
    const float* lbg = (const float*)d_in[3];
    const float* lfg = (const float*)d_in[4];
    const float* obg = (const float*)d_in[5];
    const float* ofg = (const float*)d_in[6];
    const float* sbg = (const float*)d_in[7];
    const float* sfg = (const float*)d_in[8];
    const float* lgbg = (const float*)d_in[9];
    const float* lgfg = (const float*)d_in[10];
    const float* sds = (const float*)d_in[11];
    float* out = (float*)d_out;

    // ws layout: [part f32 16*18*2304][memsB bf16 16*2304*256][kT bf16 4*2304*256]
    float* part = (float*)d_ws;
    const size_t part_bytes = (size_t)16 * 18 * HW * sizeof(float);          // ~2.65 MB
    unsigned short* memsB = (unsigned short*)((char*)d_ws + part_bytes);
    const size_t mems_bytes = (size_t)16 * HW * CD * sizeof(unsigned short); // ~18.9 MB
    unsigned short* kT = (unsigned short*)((char*)d_ws + part_bytes + mems_bytes);

    prep<<<11556, 256, 0, stream>>>(gbg, gfg, lbg, lfg, norm_key,
                                    obg, ofg, sbg, sfg, lgbg, lgfg,
                                    memsB, kT, out);
    fine_gemm<<<1296, 512, 0, stream>>>(memsB, kT, sds, part);
    finalize<<<144, 256, 0, stream>>>(part, out);
}